// Round 5
// baseline (61.622 us; speedup 1.0000x reference)
//
#include <hip/hip_runtime.h>

#define NBLK 128
#define BLK  8
#define BB   4
#define SS   4096
#define DD   1024
#define PLANE (BB * SS * DD)          // 16,777,216 floats per output plane
#define APPLY_WGS 1024
#define THREADS (APPLY_WGS * 256)     // 262,144 threads
#define NITER (PLANE / 4 / THREADS)   // 16 float4-tiles per thread

typedef float floatx4 __attribute__((ext_vector_type(4)));

// ---------------------------------------------------------------------------
// Kernel 1: Cayley transform. 128 independent 16x16 solves (real-block
// isomorphism of the 8x8 complex system). 16 threads per solve, one row
// each; row kept in registers; pivot row broadcast through LDS.
// ---------------------------------------------------------------------------
__global__ __launch_bounds__(256) void cayley_kernel(
    const float* __restrict__ Ar, const float* __restrict__ Ai,
    float* __restrict__ Ur, float* __restrict__ Ui) {
  __shared__ float piv[16][33];
  const int s = threadIdx.x >> 4;
  const int r = threadIdx.x & 15;
  const int n = blockIdx.x * 16 + s;
  const float* arb = Ar + n * 64;
  const float* aib = Ai + n * 64;

  float row[32];
  if (r < 8) {
    #pragma unroll
    for (int c = 0; c < 8; ++c) {
      float sk = 0.5f * (arb[r * 8 + c] - arb[c * 8 + r]);
      float sy = 0.5f * (aib[r * 8 + c] + aib[c * 8 + r]);
      float d  = (c == r) ? 1.0f : 0.0f;
      row[c]      = d + sk;
      row[8 + c]  = -sy;
      row[16 + c] = d - sk;
      row[24 + c] = sy;
    }
  } else {
    const int rr = r - 8;
    #pragma unroll
    for (int c = 0; c < 8; ++c) {
      float sk = 0.5f * (arb[rr * 8 + c] - arb[c * 8 + rr]);
      float sy = 0.5f * (aib[rr * 8 + c] + aib[c * 8 + rr]);
      float d  = (c == rr) ? 1.0f : 0.0f;
      row[c]      = sy;
      row[8 + c]  = d + sk;
      row[16 + c] = -sy;
      row[24 + c] = d - sk;
    }
  }

  #pragma unroll
  for (int k = 0; k < 16; ++k) {
    if (r == k) {
      float inv = 1.0f / row[k];
      #pragma unroll
      for (int j = 0; j < 32; ++j) { row[j] *= inv; piv[s][j] = row[j]; }
    }
    __syncthreads();
    if (r != k) {
      float f = row[k];
      #pragma unroll
      for (int j = 0; j < 32; ++j) row[j] = fmaf(-f, piv[s][j], row[j]);
    }
    __syncthreads();
  }

  if (r < 8) {
    #pragma unroll
    for (int c = 0; c < 8; ++c) Ur[n * 64 + r * 8 + c] = row[16 + c];
  } else {
    #pragma unroll
    for (int c = 0; c < 8; ++c) Ui[n * 64 + (r - 8) * 8 + c] = row[16 + c];
  }
}

// ---------------------------------------------------------------------------
// Kernel 2 (R5 = R4 + compile fix): one float4 (= half block, 4 output rows)
// per thread.
//  - Loads:  lane t reads float4 at flat index q = k*THREADS + G  -> byte
//    address stride 16 per lane: PERFECTLY DENSE, zero redundancy (R3 had
//    8-way duplicate reads = 8x gross L1 traffic).
//  - Block's other half comes from pair lane via __shfl_xor(.,1).
//  - U columns are loaded per-thread in [own-half, partner-half] order, so
//    no runtime select is needed; U rows (64 floats) pinned in VGPRs,
//    (n,h) constant across grid-stride (stride multiple of 256 float4s).
//  - Stores: dense float4 non-temporal (ext_vector_type for the builtin).
// 1024 wgs x 256 thr, 4 wg/CU resident, 16 tiles per thread.
// ---------------------------------------------------------------------------
__global__ __launch_bounds__(256, 4) void apply_kernel(
    const float* __restrict__ xr, const float* __restrict__ xi,
    const float* __restrict__ Urg, const float* __restrict__ Uig,
    float* __restrict__ out) {
  const int G = blockIdx.x * 256 + threadIdx.x;   // thread linear id
  const int p = G & 255;         // position within 256-float4 (=1024-elem) tile
  const int n = p >> 1;          // block index, constant per thread
  const int h = p & 1;           // which half of the block I own

  // U rows o = h*4+j, columns permuted: [0..3]=own half, [4..7]=partner half.
  float u[4][8], v[4][8];
  #pragma unroll
  for (int j = 0; j < 4; ++j) {
    const float* urow = Urg + n * 64 + (h * 4 + j) * 8;
    const float* vrow = Uig + n * 64 + (h * 4 + j) * 8;
    float4 uo = *(const float4*)(urow + h * 4);
    float4 up = *(const float4*)(urow + (h ^ 1) * 4);
    float4 vo = *(const float4*)(vrow + h * 4);
    float4 vp = *(const float4*)(vrow + (h ^ 1) * 4);
    u[j][0] = uo.x; u[j][1] = uo.y; u[j][2] = uo.z; u[j][3] = uo.w;
    u[j][4] = up.x; u[j][5] = up.y; u[j][6] = up.z; u[j][7] = up.w;
    v[j][0] = vo.x; v[j][1] = vo.y; v[j][2] = vo.z; v[j][3] = vo.w;
    v[j][4] = vp.x; v[j][5] = vp.y; v[j][6] = vp.z; v[j][7] = vp.w;
  }
  // Pin U in VGPRs (R1 failure mode: compiler sinks U loads into the loop).
  #pragma unroll
  for (int j = 0; j < 4; ++j)
    #pragma unroll
    for (int c = 0; c < 8; ++c)
      asm volatile("" : "+v"(u[j][c]), "+v"(v[j][c]));

  const float4* pxr = (const float4*)xr + G;
  const float4* pxi = (const float4*)xi + G;
  floatx4* qor = (floatx4*)out + G;
  floatx4* qoi = (floatx4*)(out + PLANE) + G;

  #pragma unroll 2
  for (int k = 0; k < NITER; ++k) {
    float4 a = *pxr;                       // my half of the block (xr)
    float4 b = *pxi;                       // my half of the block (xi)
    float oxr[4] = {a.x, a.y, a.z, a.w};
    float oxi[4] = {b.x, b.y, b.z, b.w};
    float pxr_[4], pxi_[4];
    #pragma unroll
    for (int c = 0; c < 4; ++c) {
      pxr_[c] = __shfl_xor(oxr[c], 1, 64); // partner half (xr)
      pxi_[c] = __shfl_xor(oxi[c], 1, 64); // partner half (xi)
    }

    floatx4 sr, si;
    #pragma unroll
    for (int j = 0; j < 4; ++j) {
      float r0 = u[j][0] * oxr[0];
      float i0 = u[j][0] * oxi[0];
      #pragma unroll
      for (int c = 1; c < 4; ++c) {
        r0 = fmaf(u[j][c], oxr[c], r0);
        i0 = fmaf(u[j][c], oxi[c], i0);
      }
      #pragma unroll
      for (int c = 0; c < 4; ++c) {
        r0 = fmaf(u[j][4 + c], pxr_[c], r0);
        i0 = fmaf(u[j][4 + c], pxi_[c], i0);
      }
      #pragma unroll
      for (int c = 0; c < 4; ++c) {
        r0 = fmaf(-v[j][c], oxi[c], r0);
        i0 = fmaf(v[j][c], oxr[c], i0);
      }
      #pragma unroll
      for (int c = 0; c < 4; ++c) {
        r0 = fmaf(-v[j][4 + c], pxi_[c], r0);
        i0 = fmaf(v[j][4 + c], pxr_[c], i0);
      }
      sr[j] = r0;
      si[j] = i0;
    }

    __builtin_nontemporal_store(sr, qor);
    __builtin_nontemporal_store(si, qoi);

    pxr += THREADS; pxi += THREADS; qor += THREADS; qoi += THREADS;
  }
}

extern "C" void kernel_launch(void* const* d_in, const int* in_sizes, int n_in,
                              void* d_out, int out_size, void* d_ws, size_t ws_size,
                              hipStream_t stream) {
  const float* xr = (const float*)d_in[0];
  const float* xi = (const float*)d_in[1];
  const float* Ar = (const float*)d_in[2];
  const float* Ai = (const float*)d_in[3];
  float* out = (float*)d_out;

  float* Ur = (float*)d_ws;              // 128*64 floats = 32 KB
  float* Ui = Ur + NBLK * 64;            // next 32 KB

  cayley_kernel<<<8, 256, 0, stream>>>(Ar, Ai, Ur, Ui);
  apply_kernel<<<APPLY_WGS, 256, 0, stream>>>(xr, xi, Ur, Ui, out);
}